// Round 1
// baseline (3189.688 us; speedup 1.0000x reference)
//
#include <hip/hip_runtime.h>

// forward_warp bilinear scatter-add
// im0: [B,C,H,W] fp32, flow: [B,H,W,2] fp32 (dx,dy), out: [B,C,H,W] fp32
// B=8, C=16, H=512, W=512

#define BB 8
#define CC 16
#define HH 512
#define WW 512

__global__ __launch_bounds__(256) void fwarp_kernel(
    const float* __restrict__ im0,
    const float* __restrict__ flow,
    float* __restrict__ out)
{
    const int idx = blockIdx.x * blockDim.x + threadIdx.x;  // b*H*W + h*W + w
    // W=512, H=512 are powers of two
    const int w  = idx & (WW - 1);
    const int h  = (idx >> 9) & (HH - 1);
    const int b  = idx >> 18;

    // coalesced 8B/lane flow load
    const float2 f = ((const float2*)flow)[idx];
    const float x = (float)w + f.x;
    const float y = (float)h + f.y;

    const float x0f = floorf(x);
    const float y0f = floorf(y);
    const int x0 = (int)x0f;
    const int y0 = (int)y0f;
    const int x1 = x0 + 1;
    const int y1 = y0 + 1;

    // scatter only if ALL four corners in-bounds (matches reference)
    if (x0 < 0 || x1 > WW - 1 || y0 < 0 || y1 > HH - 1) return;

    const float fx = x - x0f;
    const float fy = y - y0f;
    const float w_nw = (1.0f - fx) * (1.0f - fy);
    const float w_ne = fx * (1.0f - fy);
    const float w_sw = (1.0f - fx) * fy;
    const float w_se = fx * fy;

    const size_t plane = (size_t)HH * WW;
    const float* srcb = im0 + (size_t)b * CC * plane + (size_t)h * WW + w;
    float* dstb       = out + (size_t)b * CC * plane;

    const int o_nw = y0 * WW + x0;
    const int o_ne = y0 * WW + x1;
    const int o_sw = y1 * WW + x0;
    const int o_se = y1 * WW + x1;

#pragma unroll
    for (int c = 0; c < CC; ++c) {
        const float v = srcb[c * plane];  // coalesced across lanes (w contiguous)
        float* dc = dstb + c * plane;
        atomicAdd(dc + o_nw, v * w_nw);
        atomicAdd(dc + o_ne, v * w_ne);
        atomicAdd(dc + o_sw, v * w_sw);
        atomicAdd(dc + o_se, v * w_se);
    }
}

extern "C" void kernel_launch(void* const* d_in, const int* in_sizes, int n_in,
                              void* d_out, int out_size, void* d_ws, size_t ws_size,
                              hipStream_t stream) {
    const float* im0  = (const float*)d_in[0];
    const float* flow = (const float*)d_in[1];
    // d_in[2] is im1 (zeros) — we re-create zeros ourselves since d_out is poisoned
    float* out = (float*)d_out;

    // zero-init output (harness poisons d_out with 0xAA before every launch)
    hipMemsetAsync(out, 0, (size_t)out_size * sizeof(float), stream);

    const int n_pix = BB * HH * WW;          // 2,097,152 source pixels
    const int block = 256;
    const int grid  = n_pix / block;         // 8192 blocks
    fwarp_kernel<<<grid, block, 0, stream>>>(im0, flow, out);
}

// Round 2
// 941.634 us; speedup vs baseline: 3.3874x; 3.3874x over previous
//
#include <hip/hip_runtime.h>

// forward_warp bilinear scatter-add, LDS-privatized by destination tile.
// im0: [B,C,H,W] fp32, flow: [B,H,W,2] fp32 (dx,dy), out: [B,C,H,W] fp32
// B=8, C=16, H=512, W=512
//
// Each block OWNS a 32x32 dest tile (exclusive -> coalesced non-atomic output
// stores, no memset needed). Sources within tile+R halo are examined once
// (Phase A -> LDS records), then applied per-channel into an LDS accumulator
// (Phase B). Sources with |flow| >= R (rare for N(0,1) input, but possible)
// are handled exactly by a global-atomic fallback kernel ordered after.

#define BB 8
#define CC 16
#define HH 512
#define WW 512
#define TIL 32             // dest tile edge
#define RAD 4              // halo radius; main path requires f in [-RAD, RAD)
#define REG (TIL + 2*RAD)  // 40
#define NSRC (REG*REG)     // 1600
#define NTHR 256

__global__ __launch_bounds__(NTHR) void fwarp_tile(
    const float* __restrict__ im0,
    const float* __restrict__ flow,
    float* __restrict__ out)
{
    __shared__ unsigned int s_meta[NSRC];  // spatial(18)<<14 | (ly+1)<<7 | (lx+1); 0xFFFFFFFF = skip
    __shared__ float4 s_wts[NSRC];         // per-corner weights (nw, ne, sw, se), zeroed if out-of-tile
    __shared__ float s_acc[TIL * TIL];

    const int tid = threadIdx.x;
    const int tile = blockIdx.x;           // 8 * 16 * 16 = 2048
    const int tcx = tile & 15;
    const int tcy = (tile >> 4) & 15;
    const int b   = tile >> 8;
    const int w0  = tcx * TIL;
    const int h0  = tcy * TIL;

    const float2* flow2 = (const float2*)flow + ((size_t)b << 18);

    // ---- Phase A: build source records for the 40x40 region ----
    for (int i = tid; i < NSRC; i += NTHR) {
        const int ry = i / REG;
        const int rx = i - ry * REG;
        const int sy = h0 - RAD + ry;
        const int sx = w0 - RAD + rx;
        const bool inimg = (sx >= 0) & (sx < WW) & (sy >= 0) & (sy < HH);

        float fxv = 0.0f, fyv = 0.0f;
        if (inimg) {
            const float2 f = flow2[(sy << 9) + sx];
            fxv = f.x; fyv = f.y;
        }
        const float x = (float)sx + fxv;
        const float y = (float)sy + fyv;
        const float x0f = floorf(x);
        const float y0f = floorf(y);
        const int x0 = (int)x0f;
        const int y0 = (int)y0f;

        const bool inrange = (fxv >= -(float)RAD) & (fxv < (float)RAD) &
                             (fyv >= -(float)RAD) & (fyv < (float)RAD);
        const bool valid = inimg && inrange &&
                           (x0 >= 0) && (x0 <= WW - 2) && (y0 >= 0) && (y0 <= HH - 2);

        const float fx = x - x0f;
        const float fy = y - y0f;
        const int lx = x0 - w0;   // corner-local coords, in [-RAD-?, ...]
        const int ly = y0 - h0;

        const bool okW = (lx >= 0) & (lx < TIL);
        const bool okE = (lx + 1 >= 0) & (lx + 1 < TIL);
        const bool okN = (ly >= 0) & (ly < TIL);
        const bool okS = (ly + 1 >= 0) & (ly + 1 < TIL);

        float4 w4;
        w4.x = (valid && okN && okW) ? (1.0f - fx) * (1.0f - fy) : 0.0f;
        w4.y = (valid && okN && okE) ? fx * (1.0f - fy)          : 0.0f;
        w4.z = (valid && okS && okW) ? (1.0f - fx) * fy          : 0.0f;
        w4.w = (valid && okS && okE) ? fx * fy                   : 0.0f;

        const bool any = (w4.x != 0.0f) | (w4.y != 0.0f) | (w4.z != 0.0f) | (w4.w != 0.0f);
        unsigned m = 0xFFFFFFFFu;
        if (any) {
            // any => at least one corner in-tile => ly,lx in [-1, TIL-1]
            m = ((unsigned)((sy << 9) + sx) << 14) |
                ((unsigned)(ly + 1) << 7) |
                (unsigned)(lx + 1);
        }
        s_meta[i] = m;
        s_wts[i]  = w4;
    }
    __syncthreads();

    // ---- Phase B: per channel, accumulate in LDS, store coalesced ----
    for (int c = 0; c < CC; ++c) {
        for (int j = tid; j < TIL * TIL; j += NTHR) s_acc[j] = 0.0f;
        __syncthreads();

        const float* imc = im0 + (((size_t)(b * CC + c)) << 18);
        for (int i = tid; i < NSRC; i += NTHR) {
            const unsigned m = s_meta[i];
            if (m == 0xFFFFFFFFu) continue;
            const float4 w4 = s_wts[i];
            const float v = imc[m >> 14];
            const int lx = (int)(m & 0x7Fu) - 1;
            const int ly = (int)((m >> 7) & 0x7Fu) - 1;
            const int base = ly * TIL + lx;
            if (w4.x != 0.0f) atomicAdd(&s_acc[base], w4.x * v);
            if (w4.y != 0.0f) atomicAdd(&s_acc[base + 1], w4.y * v);
            if (w4.z != 0.0f) atomicAdd(&s_acc[base + TIL], w4.z * v);
            if (w4.w != 0.0f) atomicAdd(&s_acc[base + TIL + 1], w4.w * v);
        }
        __syncthreads();

        float* outc = out + (((size_t)(b * CC + c)) << 18);
        for (int j = tid; j < TIL * TIL; j += NTHR) {
            const int dy = j >> 5;
            const int dx = j & 31;
            outc[((h0 + dy) << 9) + (w0 + dx)] = s_acc[j];
        }
        __syncthreads();  // protect s_acc before next channel's zeroing
    }
}

// Exact fallback for sources with flow outside [-RAD, RAD): global atomic scatter.
__global__ __launch_bounds__(256) void fwarp_fallback(
    const float* __restrict__ im0,
    const float* __restrict__ flow,
    float* __restrict__ out)
{
    const int idx = blockIdx.x * blockDim.x + threadIdx.x;  // b*H*W + h*W + w
    const int w = idx & (WW - 1);
    const int h = (idx >> 9) & (HH - 1);
    const int b = idx >> 18;

    const float2 f = ((const float2*)flow)[idx];
    const bool inrange = (f.x >= -(float)RAD) & (f.x < (float)RAD) &
                         (f.y >= -(float)RAD) & (f.y < (float)RAD);
    if (inrange) return;  // handled by fwarp_tile

    const float x = (float)w + f.x;
    const float y = (float)h + f.y;
    const float x0f = floorf(x);
    const float y0f = floorf(y);
    const int x0 = (int)x0f;
    const int y0 = (int)y0f;
    if (x0 < 0 || x0 > WW - 2 || y0 < 0 || y0 > HH - 2) return;

    const float fx = x - x0f;
    const float fy = y - y0f;
    const float wnw = (1.0f - fx) * (1.0f - fy);
    const float wne = fx * (1.0f - fy);
    const float wsw = (1.0f - fx) * fy;
    const float wse = fx * fy;

    const size_t plane = (size_t)HH * WW;
    const float* srcb = im0 + (size_t)b * CC * plane + (size_t)h * WW + w;
    float* dstb       = out + (size_t)b * CC * plane;
    const int o = y0 * WW + x0;

#pragma unroll
    for (int c = 0; c < CC; ++c) {
        const float v = srcb[c * plane];
        float* dc = dstb + c * plane;
        atomicAdd(dc + o,          v * wnw);
        atomicAdd(dc + o + 1,      v * wne);
        atomicAdd(dc + o + WW,     v * wsw);
        atomicAdd(dc + o + WW + 1, v * wse);
    }
}

extern "C" void kernel_launch(void* const* d_in, const int* in_sizes, int n_in,
                              void* d_out, int out_size, void* d_ws, size_t ws_size,
                              hipStream_t stream) {
    const float* im0  = (const float*)d_in[0];
    const float* flow = (const float*)d_in[1];
    float* out = (float*)d_out;

    // Main kernel writes every output element exactly once -> no memset needed.
    const int n_tiles = BB * (HH / TIL) * (WW / TIL);  // 2048
    fwarp_tile<<<n_tiles, NTHR, 0, stream>>>(im0, flow, out);

    // Rare long-range sources: exact global-atomic scatter, ordered after.
    const int n_pix = BB * HH * WW;
    fwarp_fallback<<<n_pix / 256, 256, 0, stream>>>(im0, flow, out);
}